// Round 7
// baseline (479.073 us; speedup 1.0000x reference)
//
#include <hip/hip_runtime.h>
#include <stdint.h>

// Problem constants (from reference)
#define BATCH 4
#define SEQ   2048   // T == C == 2048
#define EMB   1024   // KEY_SIZE == VALUE_SIZE == H*64
#define NH    16
#define HD    64

typedef __attribute__((ext_vector_type(4))) float  floatx4;
typedef __attribute__((ext_vector_type(8))) short  shortx8;   // 8 bf16 = 4 VGPRs (MFMA A/B operand)

__device__ __forceinline__ unsigned short f2bf(float f) {
  // round-to-nearest-even fp32 -> bf16
  unsigned u = __builtin_bit_cast(unsigned, f);
  u += 0x7FFFu + ((u >> 16) & 1u);
  return (unsigned short)(u >> 16);
}

__device__ __forceinline__ unsigned pack2bf(float a, float b) {
  // RNE-packed pair of bf16 (low = a, high = b)
  return (unsigned)f2bf(a) | ((unsigned)f2bf(b) << 16);
}

__device__ __forceinline__ unsigned packtrunc(float a, float b) {
  // truncating pack (low = bf16(a), high = bf16(b)) in ONE v_perm_b32
#if __has_builtin(__builtin_amdgcn_perm)
  return __builtin_amdgcn_perm(__builtin_bit_cast(unsigned, b),
                               __builtin_bit_cast(unsigned, a), 0x07060302u);
#else
  return (__builtin_bit_cast(unsigned, a) >> 16) |
         (__builtin_bit_cast(unsigned, b) & 0xFFFF0000u);
#endif
}

__device__ __forceinline__ float fexp2(float x) {
#if __has_builtin(__builtin_amdgcn_exp2f)
  return __builtin_amdgcn_exp2f(x);   // raw v_exp_f32, inputs bounded
#else
  return exp2f(x);
#endif
}

__device__ __forceinline__ void gl_lds16(const void* g, void* l) {
  // async global->LDS, 16B per lane; LDS dest = wave-uniform base + lane*16
  __builtin_amdgcn_global_load_lds((const __attribute__((address_space(1))) void*)g,
                                   (__attribute__((address_space(3))) void*)l,
                                   16, 0, 0);
}

// ---------------- fp32 -> bf16 casts ----------------
__device__ __forceinline__ void cast_body(const float* __restrict__ in,
                                          unsigned short* __restrict__ out, int bb, int t) {
  size_t i = (size_t)bb * 256 + t;
  const float4* p = (const float4*)in + i * 2;
  float4 f0 = p[0], f1 = p[1];
  uint4 o;
  o.x = pack2bf(f0.x, f0.y);
  o.y = pack2bf(f0.z, f0.w);
  o.z = pack2bf(f1.x, f1.y);
  o.w = pack2bf(f1.z, f1.w);
  ((uint4*)out)[i] = o;
}

__global__ __launch_bounds__(256) void cast_bf16(const float* __restrict__ in,
                                                 unsigned short* __restrict__ out) {
  cast_body(in, out, blockIdx.x, threadIdx.x);
}

// all 7 tensors in one launch: q/k/v (4096 blocks each) + 4 weights (512 each) = 14336
__global__ __launch_bounds__(256) void cast_all(
    const float* __restrict__ q, const float* __restrict__ k, const float* __restrict__ v,
    const float* __restrict__ w0, const float* __restrict__ w1,
    const float* __restrict__ w2, const float* __restrict__ w3,
    unsigned short* __restrict__ oq, unsigned short* __restrict__ ok, unsigned short* __restrict__ ov,
    unsigned short* __restrict__ ow0, unsigned short* __restrict__ ow1,
    unsigned short* __restrict__ ow2, unsigned short* __restrict__ ow3) {
  int bb = blockIdx.x;
  const float* in; unsigned short* out;
  if      (bb < 4096)  { in = q;  out = oq; }
  else if (bb < 8192)  { in = k;  out = ok;  bb -= 4096; }
  else if (bb < 12288) { in = v;  out = ov;  bb -= 8192; }
  else if (bb < 12800) { in = w0; out = ow0; bb -= 12288; }
  else if (bb < 13312) { in = w1; out = ow1; bb -= 12800; }
  else if (bb < 13824) { in = w2; out = ow2; bb -= 13312; }
  else                 { in = w3; out = ow3; bb -= 13824; }
  cast_body(in, out, bb, threadIdx.x);
}

// 4 weight tensors in one launch (fallback path)
__global__ __launch_bounds__(256) void cast_w4(const float* __restrict__ i0, const float* __restrict__ i1,
                                               const float* __restrict__ i2, const float* __restrict__ i3,
                                               unsigned short* __restrict__ o0, unsigned short* __restrict__ o1,
                                               unsigned short* __restrict__ o2, unsigned short* __restrict__ o3) {
  int bb = blockIdx.x;
  const float* in; unsigned short* out;
  if      (bb < 512)  { in = i0; out = o0; }
  else if (bb < 1024) { in = i1; out = o1; bb -= 512; }
  else if (bb < 1536) { in = i2; out = o2; bb -= 1024; }
  else                { in = i3; out = o3; bb -= 1536; }
  cast_body(in, out, bb, threadIdx.x);
}

// ---------------- C[M,N] = scale * (A[M,K] @ Bt[N,K]^T)  (bf16 in, fp32 acc) ----------------
// 128x128 tile, BK=64 (16 k-iters), XOR-swizzled LDS (swizzle folded into DMA source addrs).
// MODE 0: bf16 row-major C.  MODE 1: fp32 row-major C.
// MODE 2: bf16 C^T with pi c-permute, written via Ts LDS staging -> coalesced vT
#define TST 136   // Ts row stride in shorts (17*8: b128-aligned, bank-spread)
template <int MODE>
__device__ __forceinline__ void gemm_body(const unsigned short* __restrict__ A,
                                          const unsigned short* __restrict__ Bt,
                                          void* __restrict__ Cp, float cscale,
                                          unsigned short* As, unsigned short* Bs,
                                          unsigned short* Ts) {
  constexpr int N = EMB, K = EMB;
  constexpr int BM = 128, BN = 128, BK = 64;
  const int t = threadIdx.x, w = t >> 6, lane = t & 63;
  const int quad = lane >> 4, lrow = lane & 15;
  const int m0 = blockIdx.y * BM, n0 = blockIdx.x * BN;
  const int wm = (w >> 1) * 64, wn = (w & 1) * 64;
  floatx4 acc[4][4] = {};

  // running swizzled source pointers: chunk q = i*256+t -> row r=q>>3, src chunk (q&7)^(r&7)
  const unsigned short* asrc[4];
  const unsigned short* bsrc[4];
#pragma unroll
  for (int i = 0; i < 4; i++) {
    int q = i * 256 + t;
    int r = q >> 3, kc = (q & 7) ^ (r & 7);
    asrc[i] = A + (size_t)(m0 + r) * K + kc * 8;
    bsrc[i] = Bt + (size_t)(n0 + r) * K + kc * 8;
  }

  for (int k0 = 0; k0 < K; k0 += BK) {
#pragma unroll
    for (int i = 0; i < 4; i++) {
      gl_lds16(asrc[i], (char*)As + (size_t)(i * 256 + w * 64) * 16);
      gl_lds16(bsrc[i], (char*)Bs + (size_t)(i * 256 + w * 64) * 16);
      asrc[i] += BK; bsrc[i] += BK;
    }
    __syncthreads();
#pragma unroll
    for (int ks = 0; ks < 2; ks++) {
      shortx8 a[4];
#pragma unroll
      for (int mi = 0; mi < 4; mi++) {
        int row = wm + mi * 16 + lrow;
        a[mi] = *(const shortx8*)(As + row * 64 + (((ks * 4 + quad) ^ (row & 7)) * 8));
      }
#pragma unroll
      for (int ni = 0; ni < 4; ni++) {
        int rowb = wn + ni * 16 + lrow;
        shortx8 b = *(const shortx8*)(Bs + rowb * 64 + (((ks * 4 + quad) ^ (rowb & 7)) * 8));
#pragma unroll
        for (int mi = 0; mi < 4; mi++)
          acc[mi][ni] = __builtin_amdgcn_mfma_f32_16x16x32_bf16(a[mi], b, acc[mi][ni], 0, 0, 0);
      }
    }
    __syncthreads();
  }

  if constexpr (MODE == 2) {
    // V^T + pi epilogue via Ts
#pragma unroll
    for (int u = 0; u < 2; u++)
#pragma unroll
      for (int ni = 0; ni < 4; ni++) {
        uint4 p;
        p.x = pack2bf(acc[2 * u][ni][0], acc[2 * u + 1][ni][0]);
        p.y = pack2bf(acc[2 * u][ni][1], acc[2 * u + 1][ni][1]);
        p.z = pack2bf(acc[2 * u][ni][2], acc[2 * u + 1][ni][2]);
        p.w = pack2bf(acc[2 * u][ni][3], acc[2 * u + 1][ni][3]);
        int col = wn + ni * 16 + lrow;           // n-local = (h-h0)*64 + d
        int cloc = wm + u * 32 + quad * 8;       // permuted c-slot base
        *(uint4*)(Ts + col * TST + cloc) = p;
      }
    __syncthreads();
    unsigned short* vTout = (unsigned short*)Cp;
    const int b = m0 >> 11, cbase = m0 & 2047, h0 = n0 >> 6;
#pragma unroll
    for (int i = 0; i < 8; i++) {
      int g = t + 256 * i;                       // 0..2047 output chunks
      int hh2 = g >> 10, d = (g >> 4) & 63, a = g & 15;
      uint4 v = *(const uint4*)(Ts + (hh2 * 64 + d) * TST + a * 8);
      *(uint4*)(vTout + ((size_t)((b * NH + h0 + hh2) * HD + d)) * SEQ + cbase + a * 8) = v;
    }
    __syncthreads();  // Ts reuse safety
  } else {
    // C/D layout: col = lane&15, row = quad*4 + reg
#pragma unroll
    for (int mi = 0; mi < 4; mi++)
#pragma unroll
      for (int ni = 0; ni < 4; ni++)
#pragma unroll
        for (int r = 0; r < 4; r++) {
          int row = m0 + wm + mi * 16 + quad * 4 + r;
          int col = n0 + wn + ni * 16 + lrow;
          float v = acc[mi][ni][r] * cscale;
          if constexpr (MODE == 1) ((float*)Cp)[(size_t)row * N + col] = v;
          else                     ((unsigned short*)Cp)[(size_t)row * N + col] = f2bf(v);
        }
  }
}

// q/k/v projections batched: blockIdx.z selects; z==2 (V) writes vT directly (fused transpose)
__global__ __launch_bounds__(256, 2) void gemm_qkv(
    const unsigned short* __restrict__ Xq, const unsigned short* __restrict__ Xk,
    const unsigned short* __restrict__ Xv,
    const unsigned short* __restrict__ Wq, const unsigned short* __restrict__ Wk,
    const unsigned short* __restrict__ Wv,
    unsigned short* __restrict__ Oq, unsigned short* __restrict__ Ok,
    unsigned short* __restrict__ OvT, float sq) {
  __shared__ unsigned short As[128 * 64];
  __shared__ unsigned short Bs[128 * 64];
  __shared__ unsigned short Ts[128 * TST];
  if (blockIdx.z == 0)      gemm_body<0>(Xq, Wq, Oq, sq,   As, Bs, Ts);
  else if (blockIdx.z == 1) gemm_body<0>(Xk, Wk, Ok, 1.0f, As, Bs, Ts);
  else                      gemm_body<2>(Xv, Wv, OvT, 1.0f, As, Bs, Ts);
}

// standalone variants for the serial fallback
__global__ __launch_bounds__(256, 2) void gemm_b(const unsigned short* __restrict__ A,
                                                 const unsigned short* __restrict__ Bt,
                                                 unsigned short* __restrict__ C, float sc) {
  __shared__ unsigned short As[128 * 64];
  __shared__ unsigned short Bs[128 * 64];
  gemm_body<0>(A, Bt, C, sc, As, Bs, nullptr);
}
__global__ __launch_bounds__(256, 2) void gemm_vt(const unsigned short* __restrict__ A,
                                                  const unsigned short* __restrict__ Bt,
                                                  unsigned short* __restrict__ C) {
  __shared__ unsigned short As[128 * 64];
  __shared__ unsigned short Bs[128 * 64];
  __shared__ unsigned short Ts[128 * TST];
  gemm_body<2>(A, Bt, C, 1.0f, As, Bs, Ts);
}
__global__ __launch_bounds__(256, 2) void gemm_o(const unsigned short* __restrict__ A,
                                                 const unsigned short* __restrict__ Bt,
                                                 float* __restrict__ C) {
  __shared__ unsigned short As[128 * 64];
  __shared__ unsigned short Bs[128 * 64];
  gemm_body<1>(A, Bt, C, 1.0f, As, Bs, nullptr);
}

// ---------------- flash attention (no-max softmax; Q in registers) ----------------
// Q pre-scaled by (1/8)*log2(e). 128-row Q tile/block, 64-col K/V tiles, DMA staging.
// Q A-fragments (16 VGPRs) loaded once from global -> no Qs LDS. LDS 21 KB -> 5 blocks/CU.
// Grid (bh=64, qtile=16): all 16 q-tiles of one (b,h) share id%8 -> same XCD -> K/V slab
// (512 KB) L2-resident per XCD instead of fetched by 8 XCDs.
__global__ __launch_bounds__(256, 5) void flash_attn(const unsigned short* __restrict__ qp,
                                                     const unsigned short* __restrict__ kp,
                                                     const unsigned short* __restrict__ vT,
                                                     unsigned short* __restrict__ ao) {
  __shared__ unsigned short Ks[64 * 64];
  __shared__ unsigned short Vts[64 * 64];
  __shared__ unsigned short Ps[4][16 * 40];  // per-wave P (mi-split), stride 40 shorts
  const int h = blockIdx.x & (NH - 1), b = blockIdx.x >> 4;
  const int t0 = blockIdx.y * 128;
  const int t = threadIdx.x, w = t >> 6, lane = t & 63;
  const int quad = lane >> 4, lrow = lane & 15;

  // Q fragments in registers: A[m=lrow][k=32*kk+quad*8+j] -> 16B contiguous global loads
  shortx8 qfrag[2][2];
#pragma unroll
  for (int kk = 0; kk < 2; kk++)
#pragma unroll
    for (int mi = 0; mi < 2; mi++) {
      int row = w * 32 + mi * 16 + lrow;
      qfrag[kk][mi] = *(const shortx8*)(qp + ((size_t)(b * SEQ + t0 + row)) * EMB +
                                        h * HD + kk * 32 + quad * 8);
    }

  // per-lane running source pointers for K/V staging (swizzle folded into src)
  const unsigned short* ksrc[2];
  const unsigned short* vsrc[2];
#pragma unroll
  for (int i = 0; i < 2; i++) {
    int p = i * 256 + t;
    int r = p >> 3, kc = (p & 7) ^ (r & 7);
    ksrc[i] = kp + ((size_t)(b * SEQ + r)) * EMB + h * HD + kc * 8;
    vsrc[i] = vT + ((size_t)((b * NH + h) * HD + r)) * SEQ + kc * 8;  // d=r, cc=kc
  }

  float l_st[2][4] = {};
  floatx4 accO[2][4] = {};

  for (int c0 = 0; c0 < SEQ; c0 += 64) {
    __syncthreads();  // prior tile's LDS reads done
#pragma unroll
    for (int i = 0; i < 2; i++) {
      gl_lds16(ksrc[i], (char*)Ks + (size_t)(i * 256 + w * 64) * 16);
      gl_lds16(vsrc[i], (char*)Vts + (size_t)(i * 256 + w * 64) * 16);
      ksrc[i] += 64 * EMB;
      vsrc[i] += 64;
    }
    __syncthreads();  // vmcnt(0) drain for the DMA

    // S = Qsc @ Ktile^T : wave w owns S rows [w*32, w*32+32); accS already log2-scaled
    floatx4 accS[2][4] = {};
#pragma unroll
    for (int kk = 0; kk < 2; kk++) {
      int qk = quad + kk * 4;
#pragma unroll
      for (int ni = 0; ni < 4; ni++) {
        int rowb = ni * 16 + lrow;
        shortx8 bfr = *(const shortx8*)(Ks + rowb * 64 + ((qk ^ (rowb & 7)) * 8));
#pragma unroll
        for (int mi = 0; mi < 2; mi++)
          accS[mi][ni] = __builtin_amdgcn_mfma_f32_16x16x32_bf16(qfrag[kk][mi], bfr, accS[mi][ni], 0, 0, 0);
      }
    }

    // two half-passes over c: p = exp2(s'), pack -> Ps, PV over 32 c'
    // in-wave DS ordering makes write->read->overwrite safe without barriers
#pragma unroll
    for (int hh = 0; hh < 2; hh++) {
      shortx8 pafr[2];
#pragma unroll
      for (int mi = 0; mi < 2; mi++) {
#pragma unroll
        for (int r = 0; r < 4; r++) {
          float p0 = fexp2(accS[mi][2 * hh][r]);
          float p1 = fexp2(accS[mi][2 * hh + 1][r]);
          l_st[mi][r] += p0 + p1;
          *(unsigned*)(&Ps[w][(quad * 4 + r) * 40 + lrow * 2]) = packtrunc(p0, p1);
        }
        pafr[mi] = *(const shortx8*)(&Ps[w][lrow * 40 + quad * 8]);
      }
#pragma unroll
      for (int nio = 0; nio < 4; nio++) {
        int d = nio * 16 + lrow;
        shortx8 bfr = *(const shortx8*)(Vts + d * 64 + ((((hh << 2) + quad) ^ (d & 7)) * 8));
#pragma unroll
        for (int mi = 0; mi < 2; mi++)
          accO[mi][nio] = __builtin_amdgcn_mfma_f32_16x16x32_bf16(pafr[mi], bfr, accO[mi][nio], 0, 0, 0);
      }
    }
  }

  // epilogue: reduce l across the 16-lane row group, normalize, store bf16
#pragma unroll
  for (int mi = 0; mi < 2; mi++)
#pragma unroll
    for (int r = 0; r < 4; r++) {
      float l = l_st[mi][r];
      l += __shfl_xor(l, 1);
      l += __shfl_xor(l, 2);
      l += __shfl_xor(l, 4);
      l += __shfl_xor(l, 8);
      float inv = 1.0f / l;
#pragma unroll
      for (int nio = 0; nio < 4; nio++) accO[mi][nio][r] *= inv;
    }
#pragma unroll
  for (int mi = 0; mi < 2; mi++)
#pragma unroll
    for (int nio = 0; nio < 4; nio++)
#pragma unroll
      for (int r = 0; r < 4; r++) {
        int row = t0 + w * 32 + mi * 16 + quad * 4 + r;
        int col = h * HD + nio * 16 + lrow;
        ao[((size_t)(b * SEQ + row)) * EMB + col] = f2bf(accO[mi][nio][r]);
      }
}

extern "C" void kernel_launch(void* const* d_in, const int* in_sizes, int n_in,
                              void* d_out, int out_size, void* d_ws, size_t ws_size,
                              hipStream_t stream) {
  const float* queries = (const float*)d_in[0];
  const float* keys    = (const float*)d_in[1];
  const float* values  = (const float*)d_in[2];
  const float* Wq      = (const float*)d_in[3];
  const float* Wk      = (const float*)d_in[4];
  const float* Wv      = (const float*)d_in[5];
  const float* Wo      = (const float*)d_in[6];

  char* ws = (char*)d_ws;
  const size_t MB = 1ull << 20;
  const float SC2 = 0.125f * 1.44269504088896341f;  // (1/sqrt(64)) * log2(e), folded into q

  unsigned short* wq_b = (unsigned short*)(ws + 0 * MB);
  unsigned short* wk_b = (unsigned short*)(ws + 2 * MB);
  unsigned short* wv_b = (unsigned short*)(ws + 4 * MB);
  unsigned short* wo_b = (unsigned short*)(ws + 6 * MB);

  dim3 gg(EMB / 128, (BATCH * SEQ) / 128);  // (8, 64)
  dim3 fg(NH * BATCH, SEQ / 128);           // (64, 16) XCD-locality swizzle

  if (ws_size >= 104 * MB) {
    // batched path: Xq 8-24 (->ao), Xk 24-40, Xv 40-56, qp 56-72, kp 72-88, vT 88-104
    unsigned short* Xq = (unsigned short*)(ws + 8 * MB);
    unsigned short* Xk = (unsigned short*)(ws + 24 * MB);
    unsigned short* Xv = (unsigned short*)(ws + 40 * MB);
    unsigned short* qp = (unsigned short*)(ws + 56 * MB);
    unsigned short* kp = (unsigned short*)(ws + 72 * MB);
    unsigned short* vT = (unsigned short*)(ws + 88 * MB);
    unsigned short* ao = Xq;   // Xq dead after gemm_qkv

    cast_all<<<14336, 256, 0, stream>>>(queries, keys, values, Wq, Wk, Wv, Wo,
                                        Xq, Xk, Xv, wq_b, wk_b, wv_b, wo_b);
    gemm_qkv<<<dim3(gg.x, gg.y, 3), 256, 0, stream>>>(Xq, Xk, Xv, wq_b, wk_b, wv_b,
                                                      qp, kp, vT, SC2);
    flash_attn<<<fg, 256, 0, stream>>>(qp, kp, vT, ao);
    gemm_o<<<gg, 256, 0, stream>>>(ao, wo_b, (float*)d_out);
  } else {
    // serial fallback (72 MB layout)
    unsigned short* X  = (unsigned short*)(ws + 8 * MB);
    unsigned short* qp = (unsigned short*)(ws + 24 * MB);
    unsigned short* kp = (unsigned short*)(ws + 40 * MB);
    unsigned short* vT = (unsigned short*)(ws + 56 * MB);
    unsigned short* ao = X;

    cast_w4<<<2048, 256, 0, stream>>>(Wq, Wk, Wv, Wo, wq_b, wk_b, wv_b, wo_b);
    cast_bf16<<<4096, 256, 0, stream>>>(queries, X);
    gemm_b<<<gg, 256, 0, stream>>>(X, wq_b, qp, SC2);
    cast_bf16<<<4096, 256, 0, stream>>>(keys, X);
    gemm_b<<<gg, 256, 0, stream>>>(X, wk_b, kp, 1.0f);
    cast_bf16<<<4096, 256, 0, stream>>>(values, X);
    gemm_vt<<<gg, 256, 0, stream>>>(X, wv_b, vT);
    flash_attn<<<fg, 256, 0, stream>>>(qp, kp, vT, ao);
    gemm_o<<<gg, 256, 0, stream>>>(ao, wo_b, (float*)d_out);
  }
}

// Round 8
// 322.424 us; speedup vs baseline: 1.4858x; 1.4858x over previous
//
#include <hip/hip_runtime.h>
#include <stdint.h>

// Problem constants (from reference)
#define BATCH 4
#define SEQ   2048   // T == C == 2048
#define EMB   1024   // KEY_SIZE == VALUE_SIZE == H*64
#define NH    16
#define HD    64

typedef __attribute__((ext_vector_type(4))) float  floatx4;
typedef __attribute__((ext_vector_type(8))) short  shortx8;   // 8 bf16 = 4 VGPRs (MFMA A/B operand)

__device__ __forceinline__ unsigned short f2bf(float f) {
  // round-to-nearest-even fp32 -> bf16
  unsigned u = __builtin_bit_cast(unsigned, f);
  u += 0x7FFFu + ((u >> 16) & 1u);
  return (unsigned short)(u >> 16);
}

__device__ __forceinline__ unsigned pack2bf(float a, float b) {
  // RNE-packed pair of bf16 (low = a, high = b)
  return (unsigned)f2bf(a) | ((unsigned)f2bf(b) << 16);
}

__device__ __forceinline__ unsigned packtrunc(float a, float b) {
  // truncating pack (low = bf16(a), high = bf16(b)) in ONE v_perm_b32
#if __has_builtin(__builtin_amdgcn_perm)
  return __builtin_amdgcn_perm(__builtin_bit_cast(unsigned, b),
                               __builtin_bit_cast(unsigned, a), 0x07060302u);
#else
  return (__builtin_bit_cast(unsigned, a) >> 16) |
         (__builtin_bit_cast(unsigned, b) & 0xFFFF0000u);
#endif
}

__device__ __forceinline__ float fexp2(float x) {
#if __has_builtin(__builtin_amdgcn_exp2f)
  return __builtin_amdgcn_exp2f(x);   // raw v_exp_f32, inputs bounded
#else
  return exp2f(x);
#endif
}

__device__ __forceinline__ void gl_lds16(const void* g, void* l) {
  // async global->LDS, 16B per lane; LDS dest = wave-uniform base + lane*16
  __builtin_amdgcn_global_load_lds((const __attribute__((address_space(1))) void*)g,
                                   (__attribute__((address_space(3))) void*)l,
                                   16, 0, 0);
}

// ---------------- fp32 -> bf16 casts ----------------
__device__ __forceinline__ void cast_body(const float* __restrict__ in,
                                          unsigned short* __restrict__ out, int bb, int t) {
  size_t i = (size_t)bb * 256 + t;
  const float4* p = (const float4*)in + i * 2;
  float4 f0 = p[0], f1 = p[1];
  uint4 o;
  o.x = pack2bf(f0.x, f0.y);
  o.y = pack2bf(f0.z, f0.w);
  o.z = pack2bf(f1.x, f1.y);
  o.w = pack2bf(f1.z, f1.w);
  ((uint4*)out)[i] = o;
}

__global__ __launch_bounds__(256) void cast_bf16(const float* __restrict__ in,
                                                 unsigned short* __restrict__ out) {
  cast_body(in, out, blockIdx.x, threadIdx.x);
}

// all 7 tensors in one launch: q/k/v (4096 blocks each) + 4 weights (512 each) = 14336
__global__ __launch_bounds__(256) void cast_all(
    const float* __restrict__ q, const float* __restrict__ k, const float* __restrict__ v,
    const float* __restrict__ w0, const float* __restrict__ w1,
    const float* __restrict__ w2, const float* __restrict__ w3,
    unsigned short* __restrict__ oq, unsigned short* __restrict__ ok, unsigned short* __restrict__ ov,
    unsigned short* __restrict__ ow0, unsigned short* __restrict__ ow1,
    unsigned short* __restrict__ ow2, unsigned short* __restrict__ ow3) {
  int bb = blockIdx.x;
  const float* in; unsigned short* out;
  if      (bb < 4096)  { in = q;  out = oq; }
  else if (bb < 8192)  { in = k;  out = ok;  bb -= 4096; }
  else if (bb < 12288) { in = v;  out = ov;  bb -= 8192; }
  else if (bb < 12800) { in = w0; out = ow0; bb -= 12288; }
  else if (bb < 13312) { in = w1; out = ow1; bb -= 12800; }
  else if (bb < 13824) { in = w2; out = ow2; bb -= 13312; }
  else                 { in = w3; out = ow3; bb -= 13824; }
  cast_body(in, out, bb, threadIdx.x);
}

// 4 weight tensors in one launch (fallback path)
__global__ __launch_bounds__(256) void cast_w4(const float* __restrict__ i0, const float* __restrict__ i1,
                                               const float* __restrict__ i2, const float* __restrict__ i3,
                                               unsigned short* __restrict__ o0, unsigned short* __restrict__ o1,
                                               unsigned short* __restrict__ o2, unsigned short* __restrict__ o3) {
  int bb = blockIdx.x;
  const float* in; unsigned short* out;
  if      (bb < 512)  { in = i0; out = o0; }
  else if (bb < 1024) { in = i1; out = o1; bb -= 512; }
  else if (bb < 1536) { in = i2; out = o2; bb -= 1024; }
  else                { in = i3; out = o3; bb -= 1536; }
  cast_body(in, out, bb, threadIdx.x);
}

// ---------------- C[M,N] = scale * (A[M,K] @ Bt[N,K]^T)  (bf16 in, fp32 acc) ----------------
// 128x128 tile, BK=64 (16 k-iters), XOR-swizzled LDS (swizzle folded into DMA source addrs).
// MODE 0: bf16 row-major C.  MODE 1: fp32 row-major C.
// MODE 2: bf16 C^T with pi c-permute, written via Ts LDS staging -> coalesced vT
#define TST 136   // Ts row stride in shorts (17*8: b128-aligned, bank-spread)
template <int MODE>
__device__ __forceinline__ void gemm_body(const unsigned short* __restrict__ A,
                                          const unsigned short* __restrict__ Bt,
                                          void* __restrict__ Cp, float cscale,
                                          unsigned short* As, unsigned short* Bs,
                                          unsigned short* Ts) {
  constexpr int N = EMB, K = EMB;
  constexpr int BM = 128, BN = 128, BK = 64;
  const int t = threadIdx.x, w = t >> 6, lane = t & 63;
  const int quad = lane >> 4, lrow = lane & 15;
  const int m0 = blockIdx.y * BM, n0 = blockIdx.x * BN;
  const int wm = (w >> 1) * 64, wn = (w & 1) * 64;
  floatx4 acc[4][4] = {};

  // running swizzled source pointers: chunk q = i*256+t -> row r=q>>3, src chunk (q&7)^(r&7)
  const unsigned short* asrc[4];
  const unsigned short* bsrc[4];
#pragma unroll
  for (int i = 0; i < 4; i++) {
    int q = i * 256 + t;
    int r = q >> 3, kc = (q & 7) ^ (r & 7);
    asrc[i] = A + (size_t)(m0 + r) * K + kc * 8;
    bsrc[i] = Bt + (size_t)(n0 + r) * K + kc * 8;
  }

  for (int k0 = 0; k0 < K; k0 += BK) {
#pragma unroll
    for (int i = 0; i < 4; i++) {
      gl_lds16(asrc[i], (char*)As + (size_t)(i * 256 + w * 64) * 16);
      gl_lds16(bsrc[i], (char*)Bs + (size_t)(i * 256 + w * 64) * 16);
      asrc[i] += BK; bsrc[i] += BK;
    }
    __syncthreads();
#pragma unroll
    for (int ks = 0; ks < 2; ks++) {
      shortx8 a[4];
#pragma unroll
      for (int mi = 0; mi < 4; mi++) {
        int row = wm + mi * 16 + lrow;
        a[mi] = *(const shortx8*)(As + row * 64 + (((ks * 4 + quad) ^ (row & 7)) * 8));
      }
#pragma unroll
      for (int ni = 0; ni < 4; ni++) {
        int rowb = wn + ni * 16 + lrow;
        shortx8 b = *(const shortx8*)(Bs + rowb * 64 + (((ks * 4 + quad) ^ (rowb & 7)) * 8));
#pragma unroll
        for (int mi = 0; mi < 4; mi++)
          acc[mi][ni] = __builtin_amdgcn_mfma_f32_16x16x32_bf16(a[mi], b, acc[mi][ni], 0, 0, 0);
      }
    }
    __syncthreads();
  }

  if constexpr (MODE == 2) {
    // V^T + pi epilogue via Ts
#pragma unroll
    for (int u = 0; u < 2; u++)
#pragma unroll
      for (int ni = 0; ni < 4; ni++) {
        uint4 p;
        p.x = pack2bf(acc[2 * u][ni][0], acc[2 * u + 1][ni][0]);
        p.y = pack2bf(acc[2 * u][ni][1], acc[2 * u + 1][ni][1]);
        p.z = pack2bf(acc[2 * u][ni][2], acc[2 * u + 1][ni][2]);
        p.w = pack2bf(acc[2 * u][ni][3], acc[2 * u + 1][ni][3]);
        int col = wn + ni * 16 + lrow;           // n-local = (h-h0)*64 + d
        int cloc = wm + u * 32 + quad * 8;       // permuted c-slot base
        *(uint4*)(Ts + col * TST + cloc) = p;
      }
    __syncthreads();
    unsigned short* vTout = (unsigned short*)Cp;
    const int b = m0 >> 11, cbase = m0 & 2047, h0 = n0 >> 6;
#pragma unroll
    for (int i = 0; i < 8; i++) {
      int g = t + 256 * i;                       // 0..2047 output chunks
      int hh2 = g >> 10, d = (g >> 4) & 63, a = g & 15;
      uint4 v = *(const uint4*)(Ts + (hh2 * 64 + d) * TST + a * 8);
      *(uint4*)(vTout + ((size_t)((b * NH + h0 + hh2) * HD + d)) * SEQ + cbase + a * 8) = v;
    }
    __syncthreads();  // Ts reuse safety
  } else {
    // C/D layout: col = lane&15, row = quad*4 + reg
#pragma unroll
    for (int mi = 0; mi < 4; mi++)
#pragma unroll
      for (int ni = 0; ni < 4; ni++)
#pragma unroll
        for (int r = 0; r < 4; r++) {
          int row = m0 + wm + mi * 16 + quad * 4 + r;
          int col = n0 + wn + ni * 16 + lrow;
          float v = acc[mi][ni][r] * cscale;
          if constexpr (MODE == 1) ((float*)Cp)[(size_t)row * N + col] = v;
          else                     ((unsigned short*)Cp)[(size_t)row * N + col] = f2bf(v);
        }
  }
}

// q/k/v projections batched: blockIdx.z selects; z==2 (V) writes vT directly (fused transpose)
__global__ __launch_bounds__(256, 2) void gemm_qkv(
    const unsigned short* __restrict__ Xq, const unsigned short* __restrict__ Xk,
    const unsigned short* __restrict__ Xv,
    const unsigned short* __restrict__ Wq, const unsigned short* __restrict__ Wk,
    const unsigned short* __restrict__ Wv,
    unsigned short* __restrict__ Oq, unsigned short* __restrict__ Ok,
    unsigned short* __restrict__ OvT, float sq) {
  __shared__ unsigned short As[128 * 64];
  __shared__ unsigned short Bs[128 * 64];
  __shared__ unsigned short Ts[128 * TST];
  if (blockIdx.z == 0)      gemm_body<0>(Xq, Wq, Oq, sq,   As, Bs, Ts);
  else if (blockIdx.z == 1) gemm_body<0>(Xk, Wk, Ok, 1.0f, As, Bs, Ts);
  else                      gemm_body<2>(Xv, Wv, OvT, 1.0f, As, Bs, Ts);
}

// standalone variants for the serial fallback
__global__ __launch_bounds__(256, 2) void gemm_b(const unsigned short* __restrict__ A,
                                                 const unsigned short* __restrict__ Bt,
                                                 unsigned short* __restrict__ C, float sc) {
  __shared__ unsigned short As[128 * 64];
  __shared__ unsigned short Bs[128 * 64];
  gemm_body<0>(A, Bt, C, sc, As, Bs, nullptr);
}
__global__ __launch_bounds__(256, 2) void gemm_vt(const unsigned short* __restrict__ A,
                                                  const unsigned short* __restrict__ Bt,
                                                  unsigned short* __restrict__ C) {
  __shared__ unsigned short As[128 * 64];
  __shared__ unsigned short Bs[128 * 64];
  __shared__ unsigned short Ts[128 * TST];
  gemm_body<2>(A, Bt, C, 1.0f, As, Bs, Ts);
}
__global__ __launch_bounds__(256, 2) void gemm_o(const unsigned short* __restrict__ A,
                                                 const unsigned short* __restrict__ Bt,
                                                 float* __restrict__ C) {
  __shared__ unsigned short As[128 * 64];
  __shared__ unsigned short Bs[128 * 64];
  gemm_body<1>(A, Bt, C, 1.0f, As, Bs, nullptr);
}

// ---------------- flash attention (no-max softmax; Q in registers) ----------------
// Q pre-scaled by (1/8)*log2(e). 128-row Q tile/block, 64-col K/V tiles, DMA staging.
// Q A-fragments (16 VGPRs) loaded once from global -> no Qs LDS. LDS 21 KB.
// __launch_bounds__(256,4): 128 regs/wave — waves/EU=5 spills accumulators to scratch
// (R7: WRITE_SIZE 16->549 MB, flash 95->250 us). 4 blocks/CU is the sweet spot.
// Grid (bh=64, qtile=16): all 16 q-tiles of one (b,h) share id%8 -> same XCD -> K/V slab
// L2-resident per XCD.
__global__ __launch_bounds__(256, 4) void flash_attn(const unsigned short* __restrict__ qp,
                                                     const unsigned short* __restrict__ kp,
                                                     const unsigned short* __restrict__ vT,
                                                     unsigned short* __restrict__ ao) {
  __shared__ unsigned short Ks[64 * 64];
  __shared__ unsigned short Vts[64 * 64];
  __shared__ unsigned short Ps[4][16 * 40];  // per-wave P (mi-split), stride 40 shorts
  const int h = blockIdx.x & (NH - 1), b = blockIdx.x >> 4;
  const int t0 = blockIdx.y * 128;
  const int t = threadIdx.x, w = t >> 6, lane = t & 63;
  const int quad = lane >> 4, lrow = lane & 15;

  // Q fragments in registers: A[m=lrow][k=32*kk+quad*8+j] -> 16B contiguous global loads
  shortx8 qfrag[2][2];
#pragma unroll
  for (int kk = 0; kk < 2; kk++)
#pragma unroll
    for (int mi = 0; mi < 2; mi++) {
      int row = w * 32 + mi * 16 + lrow;
      qfrag[kk][mi] = *(const shortx8*)(qp + ((size_t)(b * SEQ + t0 + row)) * EMB +
                                        h * HD + kk * 32 + quad * 8);
    }

  // per-lane running source pointers for K/V staging (swizzle folded into src)
  const unsigned short* ksrc[2];
  const unsigned short* vsrc[2];
#pragma unroll
  for (int i = 0; i < 2; i++) {
    int p = i * 256 + t;
    int r = p >> 3, kc = (p & 7) ^ (r & 7);
    ksrc[i] = kp + ((size_t)(b * SEQ + r)) * EMB + h * HD + kc * 8;
    vsrc[i] = vT + ((size_t)((b * NH + h) * HD + r)) * SEQ + kc * 8;  // d=r, cc=kc
  }

  float l_st[2][4] = {};
  floatx4 accO[2][4] = {};

  for (int c0 = 0; c0 < SEQ; c0 += 64) {
    __syncthreads();  // prior tile's LDS reads done
#pragma unroll
    for (int i = 0; i < 2; i++) {
      gl_lds16(ksrc[i], (char*)Ks + (size_t)(i * 256 + w * 64) * 16);
      gl_lds16(vsrc[i], (char*)Vts + (size_t)(i * 256 + w * 64) * 16);
      ksrc[i] += 64 * EMB;
      vsrc[i] += 64;
    }
    __syncthreads();  // vmcnt(0) drain for the DMA

    // S = Qsc @ Ktile^T : wave w owns S rows [w*32, w*32+32); accS already log2-scaled
    floatx4 accS[2][4] = {};
#pragma unroll
    for (int kk = 0; kk < 2; kk++) {
      int qk = quad + kk * 4;
#pragma unroll
      for (int ni = 0; ni < 4; ni++) {
        int rowb = ni * 16 + lrow;
        shortx8 bfr = *(const shortx8*)(Ks + rowb * 64 + ((qk ^ (rowb & 7)) * 8));
#pragma unroll
        for (int mi = 0; mi < 2; mi++)
          accS[mi][ni] = __builtin_amdgcn_mfma_f32_16x16x32_bf16(qfrag[kk][mi], bfr, accS[mi][ni], 0, 0, 0);
      }
    }

    // two half-passes over c: p = exp2(s'), pack -> Ps, PV over 32 c'
    // in-wave DS ordering makes write->read->overwrite safe without barriers
#pragma unroll
    for (int hh = 0; hh < 2; hh++) {
      shortx8 pafr[2];
#pragma unroll
      for (int mi = 0; mi < 2; mi++) {
#pragma unroll
        for (int r = 0; r < 4; r++) {
          float p0 = fexp2(accS[mi][2 * hh][r]);
          float p1 = fexp2(accS[mi][2 * hh + 1][r]);
          l_st[mi][r] += p0 + p1;
          *(unsigned*)(&Ps[w][(quad * 4 + r) * 40 + lrow * 2]) = packtrunc(p0, p1);
        }
        pafr[mi] = *(const shortx8*)(&Ps[w][lrow * 40 + quad * 8]);
      }
#pragma unroll
      for (int nio = 0; nio < 4; nio++) {
        int d = nio * 16 + lrow;
        shortx8 bfr = *(const shortx8*)(Vts + d * 64 + ((((hh << 2) + quad) ^ (d & 7)) * 8));
#pragma unroll
        for (int mi = 0; mi < 2; mi++)
          accO[mi][nio] = __builtin_amdgcn_mfma_f32_16x16x32_bf16(pafr[mi], bfr, accO[mi][nio], 0, 0, 0);
      }
    }
  }

  // epilogue: reduce l across the 16-lane row group, normalize, store bf16
#pragma unroll
  for (int mi = 0; mi < 2; mi++)
#pragma unroll
    for (int r = 0; r < 4; r++) {
      float l = l_st[mi][r];
      l += __shfl_xor(l, 1);
      l += __shfl_xor(l, 2);
      l += __shfl_xor(l, 4);
      l += __shfl_xor(l, 8);
      float inv = 1.0f / l;
#pragma unroll
      for (int nio = 0; nio < 4; nio++) accO[mi][nio][r] *= inv;
    }
#pragma unroll
  for (int mi = 0; mi < 2; mi++)
#pragma unroll
    for (int nio = 0; nio < 4; nio++)
#pragma unroll
      for (int r = 0; r < 4; r++) {
        int row = t0 + w * 32 + mi * 16 + quad * 4 + r;
        int col = h * HD + nio * 16 + lrow;
        ao[((size_t)(b * SEQ + row)) * EMB + col] = f2bf(accO[mi][nio][r]);
      }
}

extern "C" void kernel_launch(void* const* d_in, const int* in_sizes, int n_in,
                              void* d_out, int out_size, void* d_ws, size_t ws_size,
                              hipStream_t stream) {
  const float* queries = (const float*)d_in[0];
  const float* keys    = (const float*)d_in[1];
  const float* values  = (const float*)d_in[2];
  const float* Wq      = (const float*)d_in[3];
  const float* Wk      = (const float*)d_in[4];
  const float* Wv      = (const float*)d_in[5];
  const float* Wo      = (const float*)d_in[6];

  char* ws = (char*)d_ws;
  const size_t MB = 1ull << 20;
  const float SC2 = 0.125f * 1.44269504088896341f;  // (1/sqrt(64)) * log2(e), folded into q

  unsigned short* wq_b = (unsigned short*)(ws + 0 * MB);
  unsigned short* wk_b = (unsigned short*)(ws + 2 * MB);
  unsigned short* wv_b = (unsigned short*)(ws + 4 * MB);
  unsigned short* wo_b = (unsigned short*)(ws + 6 * MB);

  dim3 gg(EMB / 128, (BATCH * SEQ) / 128);  // (8, 64)
  dim3 fg(NH * BATCH, SEQ / 128);           // (64, 16) XCD-locality swizzle

  if (ws_size >= 104 * MB) {
    // batched path: Xq 8-24 (->ao), Xk 24-40, Xv 40-56, qp 56-72, kp 72-88, vT 88-104
    unsigned short* Xq = (unsigned short*)(ws + 8 * MB);
    unsigned short* Xk = (unsigned short*)(ws + 24 * MB);
    unsigned short* Xv = (unsigned short*)(ws + 40 * MB);
    unsigned short* qp = (unsigned short*)(ws + 56 * MB);
    unsigned short* kp = (unsigned short*)(ws + 72 * MB);
    unsigned short* vT = (unsigned short*)(ws + 88 * MB);
    unsigned short* ao = Xq;   // Xq dead after gemm_qkv

    cast_all<<<14336, 256, 0, stream>>>(queries, keys, values, Wq, Wk, Wv, Wo,
                                        Xq, Xk, Xv, wq_b, wk_b, wv_b, wo_b);
    gemm_qkv<<<dim3(gg.x, gg.y, 3), 256, 0, stream>>>(Xq, Xk, Xv, wq_b, wk_b, wv_b,
                                                      qp, kp, vT, SC2);
    flash_attn<<<fg, 256, 0, stream>>>(qp, kp, vT, ao);
    gemm_o<<<gg, 256, 0, stream>>>(ao, wo_b, (float*)d_out);
  } else {
    // serial fallback (72 MB layout)
    unsigned short* X  = (unsigned short*)(ws + 8 * MB);
    unsigned short* qp = (unsigned short*)(ws + 24 * MB);
    unsigned short* kp = (unsigned short*)(ws + 40 * MB);
    unsigned short* vT = (unsigned short*)(ws + 56 * MB);
    unsigned short* ao = X;

    cast_w4<<<2048, 256, 0, stream>>>(Wq, Wk, Wv, Wo, wq_b, wk_b, wv_b, wo_b);
    cast_bf16<<<4096, 256, 0, stream>>>(queries, X);
    gemm_b<<<gg, 256, 0, stream>>>(X, wq_b, qp, SC2);
    cast_bf16<<<4096, 256, 0, stream>>>(keys, X);
    gemm_b<<<gg, 256, 0, stream>>>(X, wk_b, kp, 1.0f);
    cast_bf16<<<4096, 256, 0, stream>>>(values, X);
    gemm_vt<<<gg, 256, 0, stream>>>(X, wv_b, vT);
    flash_attn<<<fg, 256, 0, stream>>>(qp, kp, vT, ao);
    gemm_o<<<gg, 256, 0, stream>>>(ao, wo_b, (float*)d_out);
  }
}